// Round 6
// baseline (114.375 us; speedup 1.0000x reference)
//
#include <hip/hip_runtime.h>
#include <hip/hip_bf16.h>

#define BB 16
#define NQ 64
#define NK 512
#define HD 256   // H = QS = KS = VD = 256

typedef __attribute__((ext_vector_type(8))) short short8;
typedef __attribute__((ext_vector_type(4))) float f32x4;

__device__ __forceinline__ ushort bf16_rne(float v) {
    unsigned u = __float_as_uint(v);
    return (ushort)((u + 0x7FFFu + ((u >> 16) & 1u)) >> 16);
}
__device__ __forceinline__ float bf16_to_f(ushort h) {
    return __uint_as_float(((unsigned)h) << 16);
}

// Raw barrier that drains ONLY LDS (lgkmcnt); global loads stay in flight.
// (hipcc's __syncthreads drains vmcnt(0) too, which serialized every
// prefetch in rounds 1-4.)  Fences on BOTH sides: s_barrier is not a
// memory fence in LLVM's model, so post-barrier LDS reads could otherwise
// be hoisted above it (m152 race class).
#define BARRIER_LGKM() do { \
    asm volatile("s_waitcnt lgkmcnt(0)" ::: "memory"); \
    __builtin_amdgcn_s_barrier(); \
    asm volatile("" ::: "memory"); \
} while (0)

// ---------------------------------------------------------------------------
// W-only conversion (tiny): W fp32 [k][n] -> hi/lo bf16 TRANSPOSED [n][k].
// ---------------------------------------------------------------------------
__global__ __launch_bounds__(256) void wconv(
    const float* __restrict__ wq, const float* __restrict__ wk,
    ushort* __restrict__ wqh, ushort* __restrict__ wql,
    ushort* __restrict__ wkh, ushort* __restrict__ wkl)
{
    int widx = blockIdx.x * 256 + threadIdx.x;     // 0..32767
    const float* W; ushort *wh, *wl;
    if (widx < 16384) { W = wq; wh = wqh; wl = wql; }
    else { W = wk; wh = wkh; wl = wkl; widx -= 16384; }
    int n  = widx >> 6;
    int k4 = (widx & 63) * 4;
    ushort hh[4], ll[4];
    #pragma unroll
    for (int c = 0; c < 4; ++c) {
        float v = W[(k4 + c) * 256 + n];
        hh[c] = bf16_rne(v);
        ll[c] = bf16_rne(v - bf16_to_f(hh[c]));
    }
    *(ushort4*)&wh[n * 256 + k4] = make_ushort4(hh[0], hh[1], hh[2], hh[3]);
    *(ushort4*)&wl[n * 256 + k4] = make_ushort4(ll[0], ll[1], ll[2], ll[3]);
}

// ---------------------------------------------------------------------------
// Projection GEMM with FUSED A-conversion (unchanged from round 4).
// epilogue: exp2(acc*scale) so score kernel consumes EQ=e^{2q}, EK=e^{2k}.
// ---------------------------------------------------------------------------
__global__ __launch_bounds__(256, 2) void proj_fused(
    const float* __restrict__ queries, const float* __restrict__ keys,
    const ushort* __restrict__ wqh, const ushort* __restrict__ wql,
    const ushort* __restrict__ wkh, const ushort* __restrict__ wkl,
    float* __restrict__ qp, float* __restrict__ kp, float scale)
{
    __shared__ ushort AsH[64 * 64], AsL[64 * 64];
    __shared__ ushort BsH[64 * 64], BsL[64 * 64];

    const float* A; const ushort *Bh, *Bl; float* C; int rows0;
    const int bx = blockIdx.x;
    if (bx < 16) { A = queries; Bh = wqh; Bl = wql; C = qp; rows0 = bx * 64; }
    else         { A = keys;    Bh = wkh; Bl = wkl; C = kp; rows0 = (bx - 16) * 64; }
    const int cols0 = blockIdx.y * 64;

    const int t = threadIdx.x, lane = t & 63, wave = t >> 6;
    const int quad = lane >> 4, l15 = lane & 15;
    const int sr  = t >> 2;
    const int sc2 = (t & 3) * 2;

    f32x4 acc[4];
    #pragma unroll
    for (int j = 0; j < 4; ++j) acc[j] = (f32x4){0.f, 0.f, 0.f, 0.f};

    for (int k0 = 0; k0 < 256; k0 += 64) {
        const float* arow = &A[(size_t)(rows0 + sr) * 256 + k0 + sc2 * 8];
        float4 a0 = *(const float4*)&arow[0];
        float4 a1 = *(const float4*)&arow[4];
        float4 a2 = *(const float4*)&arow[8];
        float4 a3 = *(const float4*)&arow[12];
        const ushort* bhp = &Bh[(size_t)(cols0 + sr) * 256 + k0 + sc2 * 8];
        const ushort* blp = &Bl[(size_t)(cols0 + sr) * 256 + k0 + sc2 * 8];
        short8 b0h = *(const short8*)&bhp[0];
        short8 b1h = *(const short8*)&bhp[8];
        short8 b0l = *(const short8*)&blp[0];
        short8 b1l = *(const short8*)&blp[8];

        __syncthreads();

        float av[16] = {a0.x, a0.y, a0.z, a0.w, a1.x, a1.y, a1.z, a1.w,
                        a2.x, a2.y, a2.z, a2.w, a3.x, a3.y, a3.z, a3.w};
        short8 ah0, ah1, al0, al1;
        #pragma unroll
        for (int e = 0; e < 8; ++e) {
            ushort h0 = bf16_rne(av[e]);
            ushort h1 = bf16_rne(av[8 + e]);
            ah0[e] = (short)h0;
            ah1[e] = (short)h1;
            al0[e] = (short)bf16_rne(av[e] - bf16_to_f(h0));
            al1[e] = (short)bf16_rne(av[8 + e] - bf16_to_f(h1));
        }
        {
            int s0 = sr * 8 + ((sc2 + 0) ^ (sr & 7));
            int s1 = sr * 8 + ((sc2 + 1) ^ (sr & 7));
            *(short8*)&AsH[s0 * 8] = ah0;
            *(short8*)&AsH[s1 * 8] = ah1;
            *(short8*)&AsL[s0 * 8] = al0;
            *(short8*)&AsL[s1 * 8] = al1;
            *(short8*)&BsH[s0 * 8] = b0h;
            *(short8*)&BsH[s1 * 8] = b1h;
            *(short8*)&BsL[s0 * 8] = b0l;
            *(short8*)&BsL[s1 * 8] = b1l;
        }
        __syncthreads();

        #pragma unroll
        for (int ks = 0; ks < 2; ++ks) {
            const int c = ks * 4 + quad;
            short8 aH, aL, bH[4], bL[4];
            {
                int r = wave * 16 + l15;
                int slot = r * 8 + (c ^ (r & 7));
                aH = *(const short8*)&AsH[slot * 8];
                aL = *(const short8*)&AsL[slot * 8];
            }
            #pragma unroll
            for (int ns = 0; ns < 4; ++ns) {
                int n = ns * 16 + l15;
                int slot = n * 8 + (c ^ (n & 7));
                bH[ns] = *(const short8*)&BsH[slot * 8];
                bL[ns] = *(const short8*)&BsL[slot * 8];
            }
            #pragma unroll
            for (int ns = 0; ns < 4; ++ns)
                acc[ns] = __builtin_amdgcn_mfma_f32_16x16x32_bf16(aH, bH[ns], acc[ns], 0, 0, 0);
            #pragma unroll
            for (int ns = 0; ns < 4; ++ns)
                acc[ns] = __builtin_amdgcn_mfma_f32_16x16x32_bf16(aL, bH[ns], acc[ns], 0, 0, 0);
            #pragma unroll
            for (int ns = 0; ns < 4; ++ns)
                acc[ns] = __builtin_amdgcn_mfma_f32_16x16x32_bf16(aH, bL[ns], acc[ns], 0, 0, 0);
        }
    }

    const int rbase = rows0 + wave * 16 + quad * 4;
    #pragma unroll
    for (int ns = 0; ns < 4; ++ns) {
        int col = cols0 + ns * 16 + l15;
        #pragma unroll
        for (int r = 0; r < 4; ++r)
            C[(size_t)(rbase + r) * 256 + col] =
                __builtin_amdgcn_exp2f(acc[ns][r] * scale);
    }
}

// ---------------------------------------------------------------------------
// PERSISTENT fused score+PV+combine.  Block = (b, q-tile of 4 rows); loops
// over its nc=ceil(vl/64) alive 64-key segments.  8 waves x 512 thr; wave
// owns 8 keys x full H (lane = key8*8 + ch8).  No-max softmax => O and L
// accumulate in registers across segments; final cross-wave reduce writes
// `out` directly (combine kernel deleted).
// Pipelining: ek double-banked (ekA/ekB) - next seg's ek issued before the
// current score loop; v ring reloaded inside PV.  The ONE per-seg barrier
// drains lgkmcnt only (raw s_barrier), so global prefetches survive it --
// the mechanism that nullified rounds 2-4's prefetching.
// Ps double-buffered: seg s+2's write to Ps[s&1] happens after barrier s+1,
// by which time all waves finished PV reads of seg s (WAR-safe).
// ---------------------------------------------------------------------------
__global__ __launch_bounds__(512) void score_fused(
    const float* __restrict__ qp,      // [B*NQ, H]  EQ = exp2(q * 2/ln2)
    const float* __restrict__ kp,      // [B*NK, H]  EK = exp2(k * 2/ln2)
    const float* __restrict__ values,  // [B, NK, VD]
    const int*   __restrict__ vlens,   // [B]
    const float* __restrict__ w_v,     // [H]
    float* __restrict__ out)           // [B*NQ, VD]
{
    __shared__ float eq[4][260];
    __shared__ float wv[HD];
    __shared__ float Ps[2][4][66];
    __shared__ float part[8][4][260];
    __shared__ float Lbuf[8][4];

    const int b  = blockIdx.x;          // 0..15
    const int qt = blockIdx.y;          // 0..15 (4 q rows each)
    const int vl = vlens[b];
    const int nc = (vl + 63) >> 6;

    const int t = threadIdx.x, lane = t & 63, wave = t >> 6;   // 8 waves
    const int key8 = lane >> 3;         // 0..7: key within wave's 8
    const int ch8  = lane & 7;          // 0..7: h-channel group
    const int wkey = wave * 8 + key8;   // 0..63: key within segment
    const float L2E = 1.4426950408889634f;

    const float* kbase = kp + (size_t)b * NK * HD;
    const float* vbase = values + (size_t)b * NK * HD;

    // ---- issue seg0 ek (bank A) + seg0 v ring (before staging loads) ----
    float4 ekA[8], ekB[8], vv[8];
    {
        const float* kr = kbase + (size_t)wkey * HD + ch8 * 4;
        #pragma unroll
        for (int j = 0; j < 8; ++j) ekA[j] = *(const float4*)&kr[j * 32];
        #pragma unroll
        for (int i = 0; i < 8; ++i)
            vv[i] = *(const float4*)&vbase[(size_t)(wave * 8 + i) * HD + lane * 4];
    }

    // ---- stage eq (4 rows x 256) and wv ----
    const float* qsrc = qp + ((size_t)b * NQ + qt * 4) * HD;
    if (t < 256) {
        int row = t >> 6, c4 = (t & 63) * 4;
        *(float4*)&eq[row][c4] = *(const float4*)&qsrc[(size_t)row * HD + c4];
    } else if (t < 320) {
        int i = t - 256;
        *(float4*)&wv[i * 4] = *(const float4*)&w_v[i * 4];
    }
    BARRIER_LGKM();

    float Wsum;
    {
        float ws = wv[lane] + wv[lane + 64] + wv[lane + 128] + wv[lane + 192];
        #pragma unroll
        for (int off = 32; off; off >>= 1) ws += __shfl_xor(ws, off);
        Wsum = ws;
    }

    f32x4 acc[4];
    #pragma unroll
    for (int qi = 0; qi < 4; ++qi) acc[qi] = (f32x4){0.f, 0.f, 0.f, 0.f};
    float Lacc[4] = {0.f, 0.f, 0.f, 0.f};

#define SEG_STEP(EKCUR, EKNXT)                                               \
    {                                                                        \
        if (seg + 1 < nc) {                                                  \
            const float* kr = kbase + (size_t)((seg + 1) * 64 + wkey) * HD + ch8 * 4; \
            _Pragma("unroll")                                                \
            for (int j = 0; j < 8; ++j) EKNXT[j] = *(const float4*)&kr[j * 32]; \
        }                                                                    \
        float sA[4] = {0.f, 0.f, 0.f, 0.f};                                  \
        _Pragma("unroll")                                                    \
        for (int j = 0; j < 8; ++j) {                                        \
            const int h = j * 32 + ch8 * 4;                                  \
            float4 e4 = EKCUR[j];                                            \
            float4 w4 = *(const float4*)&wv[h];                              \
            _Pragma("unroll")                                                \
            for (int qi = 0; qi < 4; ++qi) {                                 \
                float4 q4 = *(const float4*)&eq[qi][h];                      \
                float p0 = fmaf(q4.x, e4.x, 1.f);                            \
                float p1 = fmaf(q4.y, e4.y, 1.f);                            \
                float p2 = fmaf(q4.z, e4.z, 1.f);                            \
                float p3 = fmaf(q4.w, e4.w, 1.f);                            \
                float d01 = p0 * p1, d23 = p2 * p3;                          \
                float n01 = fmaf(w4.x, p1, w4.y * p0);                       \
                float n23 = fmaf(w4.z, p3, w4.w * p2);                       \
                float num = fmaf(d01, n23, d23 * n01);                       \
                float r   = __builtin_amdgcn_rcpf(d01 * d23);                \
                sA[qi] = fmaf(num, r, sA[qi]);                               \
            }                                                                \
        }                                                                    \
        _Pragma("unroll")                                                    \
        for (int qi = 0; qi < 4; ++qi) {                                     \
            sA[qi] += __shfl_xor(sA[qi], 1);                                 \
            sA[qi] += __shfl_xor(sA[qi], 2);                                 \
            sA[qi] += __shfl_xor(sA[qi], 4);                                 \
        }                                                                    \
        const bool masked = (seg * 64 + wkey >= vl);                         \
        const int pb = seg & 1;                                              \
        _Pragma("unroll")                                                    \
        for (int qi = 0; qi < 4; ++qi) {                                     \
            float sv = fmaf(-2.f, sA[qi], Wsum);                             \
            float e  = masked ? 0.f : __builtin_amdgcn_exp2f(sv * L2E);      \
            Lacc[qi] += e;                                                   \
            if (ch8 == 0) Ps[pb][qi][wkey] = e;                              \
        }                                                                    \
        BARRIER_LGKM();                                                      \
        _Pragma("unroll")                                                    \
        for (int i = 0; i < 8; ++i) {                                        \
            float4 v = vv[i];                                                \
            if (seg + 1 < nc)                                                \
                vv[i] = *(const float4*)&vbase[(size_t)((seg + 1) * 64 + wave * 8 + i) * HD + lane * 4]; \
            _Pragma("unroll")                                                \
            for (int qi = 0; qi < 4; ++qi) {                                 \
                float p = Ps[pb][qi][wave * 8 + i];                          \
                acc[qi][0] = fmaf(p, v.x, acc[qi][0]);                       \
                acc[qi][1] = fmaf(p, v.y, acc[qi][1]);                       \
                acc[qi][2] = fmaf(p, v.z, acc[qi][2]);                       \
                acc[qi][3] = fmaf(p, v.w, acc[qi][3]);                       \
            }                                                                \
        }                                                                    \
    }

    int seg = 0;
    while (true) {
        SEG_STEP(ekA, ekB)
        if (++seg >= nc) break;
        SEG_STEP(ekB, ekA)
        if (++seg >= nc) break;
    }
#undef SEG_STEP

    // ---- epilogue: per-wave L (each key's e replicated 8x -> /8) + parts ----
    #pragma unroll
    for (int qi = 0; qi < 4; ++qi) {
        float l = Lacc[qi];
        #pragma unroll
        for (int off = 32; off; off >>= 1) l += __shfl_xor(l, off);
        if (lane == 0) Lbuf[wave][qi] = l * 0.125f;
        *(f32x4*)&part[wave][qi][lane * 4] = acc[qi];
    }
    BARRIER_LGKM();

    if (t < 256) {
        int qi = t >> 6, c4 = (t & 63) * 4;
        float ox = 0.f, oy = 0.f, oz = 0.f, ow = 0.f, L = 0.f;
        #pragma unroll
        for (int w = 0; w < 8; ++w) {
            float4 p = *(const float4*)&part[w][qi][c4];
            ox += p.x; oy += p.y; oz += p.z; ow += p.w;
            L += Lbuf[w][qi];
        }
        float r = __builtin_amdgcn_rcpf(L);
        float4 o = make_float4(ox * r, oy * r, oz * r, ow * r);
        *(float4*)&out[((size_t)(b * NQ + qt * 4 + qi)) * 256 + c4] = o;
    }
}

extern "C" void kernel_launch(void* const* d_in, const int* in_sizes, int n_in,
                              void* d_out, int out_size, void* d_ws, size_t ws_size,
                              hipStream_t stream) {
    const float* queries = (const float*)d_in[0];
    const float* keys    = (const float*)d_in[1];
    const float* values  = (const float*)d_in[2];
    const int*   vlens   = (const int*)d_in[3];
    const float* W_q     = (const float*)d_in[4];
    const float* W_k     = (const float*)d_in[5];
    const float* w_v     = (const float*)d_in[6];
    float* out = (float*)d_out;

    // ws layout (~9.5 MB of 256 MiB):
    float*  kp  = (float*)d_ws;                          // 8 MB
    float*  qp  = kp + (size_t)BB * NK * HD;             // 1 MB
    ushort* wqh = (ushort*)(qp + (size_t)BB * NQ * HD);
    ushort* wql = wqh + 65536;
    ushort* wkh = wql + 65536;
    ushort* wkl = wkh + 65536;

    const float SC = 2.885390081777927f;                 // 2/ln(2)

    wconv<<<dim3(128), 256, 0, stream>>>(W_q, W_k, wqh, wql, wkh, wkl);
    proj_fused<<<dim3(144, 4), 256, 0, stream>>>(queries, keys,
                                                 wqh, wql, wkh, wkl,
                                                 qp, kp, SC);
    score_fused<<<dim3(16, 16), 512, 0, stream>>>(qp, kp, values, vlens, w_v,
                                                  out);
}